// Round 2
// baseline (562.782 us; speedup 1.0000x reference)
//
#include <hip/hip_runtime.h>
#include <hip/hip_bf16.h>
#include <stdint.h>
#include <stddef.h>

typedef short bf16x8 __attribute__((ext_vector_type(8)));
typedef float f32x4 __attribute__((ext_vector_type(4)));

#define HW 4096
#define WDIM 64

__device__ __forceinline__ short f2bf(float f) {
  union { __hip_bfloat16 b; short s; } u;
  u.b = __float2bfloat16(f);
  return u.s;
}
__device__ __forceinline__ float bf2f(short s) {
  union { unsigned u; float f; } u;
  u.u = ((unsigned)(unsigned short)s) << 16;
  return u.f;
}

// ---------------- prep: gather/convert weights (hi/lo split) + bias ----------------
__global__ void prep_weights(const float* __restrict__ w0, const float* __restrict__ w1,
                             const float* __restrict__ w2, const float* __restrict__ b0,
                             const float* __restrict__ b1, const float* __restrict__ b2,
                             const float* __restrict__ pw,
                             short* __restrict__ Wh, short* __restrict__ Wl,
                             short* __restrict__ Ph, short* __restrict__ Pl,
                             float* __restrict__ bias_sel) {
  int idx = blockIdx.x * 256 + threadIdx.x;
  if (idx < 768 * 256) {
    int j = idx >> 8;
    int h = (j & 255) >> 5;                       // head for this output row
    const float* w = (h < 4) ? w0 : ((h < 7) ? w1 : w2);
    float v = w[idx];
    short hi = f2bf(v);
    Wh[idx] = hi;
    Wl[idx] = f2bf(v - bf2f(hi));
  } else if (idx < 768 * 256 + 256 * 256) {
    int k = idx - 768 * 256;
    float v = pw[k];
    short hi = f2bf(v);
    Ph[k] = hi;
    Pl[k] = f2bf(v - bf2f(hi));
  } else if (idx < 768 * 256 + 256 * 256 + 768) {
    int j = idx - (768 * 256 + 256 * 256);
    int h = (j & 255) >> 5;
    const float* bb = (h < 4) ? b0 : ((h < 7) ? b1 : b2);
    bias_sel[j] = bb[j];
  }
}

// ---------------- transpose x: (B,256,HW) f32 -> XT (B,HW,256) bf16 hi/lo ----------------
__global__ void transpose_x(const float* __restrict__ x, short* __restrict__ XTh,
                            short* __restrict__ XTl) {
  __shared__ float tile[32][33];
  int b = blockIdx.z;
  int p0 = blockIdx.x * 32, c0 = blockIdx.y * 32;
  int tx = threadIdx.x, ty = threadIdx.y;       // 32 x 8
  const float* xb = x + (size_t)b * 256 * HW;
  #pragma unroll
  for (int i = 0; i < 32; i += 8)
    tile[ty + i][tx] = xb[(size_t)(c0 + ty + i) * HW + p0 + tx];
  __syncthreads();
  size_t ob = (size_t)b * HW * 256;
  #pragma unroll
  for (int i = 0; i < 32; i += 8) {
    float v = tile[tx][ty + i];
    short hi = f2bf(v);
    size_t o = ob + (size_t)(p0 + ty + i) * 256 + c0 + tx;
    XTh[o] = hi;
    XTl[o] = f2bf(v - bf2f(hi));
  }
}

// ---------------- split-bf16 MFMA GEMM: C[b][m][p] = sum_c A[m,c]*Bm[b][p][c] + bias[m] ----------
// A = Ah+Al (Mx256), Bm = Bh+Bl (per-batch 4096x256, k-contiguous). 3 MFMAs: hh + hl + lh.
// grid: (32, M/128, B), 256 threads (4 waves as 2x2 of 64x64 sub-tiles).
__global__ __launch_bounds__(256) void gemm_split(
    const short* __restrict__ Ah, const short* __restrict__ Al,
    const short* __restrict__ Bh, const short* __restrict__ Bl,
    const float* __restrict__ bias, float* __restrict__ C, int M) {
  constexpr int LD = 40;                          // shorts; 80B row stride
  __shared__ short Ash[128 * LD], Asl[128 * LD], Bsh[128 * LD], Bsl[128 * LD];
  int tid = threadIdx.x;
  int b = blockIdx.z;
  size_t aoff = (size_t)blockIdx.y * 128 * 256;
  size_t boff = (size_t)b * HW * 256 + (size_t)blockIdx.x * 128 * 256;
  int lane = tid & 63, wid = tid >> 6;
  int wm = wid >> 1, wn = wid & 1;
  int il = lane & 15, kg = lane >> 4;
  f32x4 acc[4][4] = {};
  int row_s = tid >> 2;                            // 0..63
  int kk_s = (tid & 3) * 8;                        // 0,8,16,24

  for (int kt = 0; kt < 256; kt += 32) {
    size_t ga0 = aoff + (size_t)row_s * 256 + kt + kk_s;
    size_t ga1 = aoff + (size_t)(row_s + 64) * 256 + kt + kk_s;
    size_t gb0 = boff + (size_t)row_s * 256 + kt + kk_s;
    size_t gb1 = boff + (size_t)(row_s + 64) * 256 + kt + kk_s;
    bf16x8 rah0 = *(const bf16x8*)&Ah[ga0];
    bf16x8 rah1 = *(const bf16x8*)&Ah[ga1];
    bf16x8 ral0 = *(const bf16x8*)&Al[ga0];
    bf16x8 ral1 = *(const bf16x8*)&Al[ga1];
    bf16x8 rbh0 = *(const bf16x8*)&Bh[gb0];
    bf16x8 rbh1 = *(const bf16x8*)&Bh[gb1];
    bf16x8 rbl0 = *(const bf16x8*)&Bl[gb0];
    bf16x8 rbl1 = *(const bf16x8*)&Bl[gb1];
    __syncthreads();
    *(bf16x8*)&Ash[row_s * LD + kk_s] = rah0;
    *(bf16x8*)&Ash[(row_s + 64) * LD + kk_s] = rah1;
    *(bf16x8*)&Asl[row_s * LD + kk_s] = ral0;
    *(bf16x8*)&Asl[(row_s + 64) * LD + kk_s] = ral1;
    *(bf16x8*)&Bsh[row_s * LD + kk_s] = rbh0;
    *(bf16x8*)&Bsh[(row_s + 64) * LD + kk_s] = rbh1;
    *(bf16x8*)&Bsl[row_s * LD + kk_s] = rbl0;
    *(bf16x8*)&Bsl[(row_s + 64) * LD + kk_s] = rbl1;
    __syncthreads();
    bf16x8 afh[4], afl[4], bfh[4], bfl[4];
    #pragma unroll
    for (int mr = 0; mr < 4; ++mr) {
      int r = (wm * 64 + mr * 16 + il) * LD + kg * 8;
      afh[mr] = *(bf16x8*)&Ash[r];
      afl[mr] = *(bf16x8*)&Asl[r];
    }
    #pragma unroll
    for (int nr = 0; nr < 4; ++nr) {
      int r = (wn * 64 + nr * 16 + il) * LD + kg * 8;
      bfh[nr] = *(bf16x8*)&Bsh[r];
      bfl[nr] = *(bf16x8*)&Bsl[r];
    }
    #pragma unroll
    for (int mr = 0; mr < 4; ++mr)
      #pragma unroll
      for (int nr = 0; nr < 4; ++nr) {
        acc[mr][nr] = __builtin_amdgcn_mfma_f32_16x16x32_bf16(afh[mr], bfh[nr], acc[mr][nr], 0, 0, 0);
        acc[mr][nr] = __builtin_amdgcn_mfma_f32_16x16x32_bf16(afh[mr], bfl[nr], acc[mr][nr], 0, 0, 0);
        acc[mr][nr] = __builtin_amdgcn_mfma_f32_16x16x32_bf16(afl[mr], bfh[nr], acc[mr][nr], 0, 0, 0);
      }
  }

  size_t cbase = (size_t)b * M * HW;
  int m0 = blockIdx.y * 128, n0 = blockIdx.x * 128;
  #pragma unroll
  for (int mr = 0; mr < 4; ++mr) {
    #pragma unroll
    for (int nr = 0; nr < 4; ++nr) {
      int grow0 = m0 + wm * 64 + mr * 16 + kg * 4;
      int gcol = n0 + wn * 64 + nr * 16 + il;
      #pragma unroll
      for (int r = 0; r < 4; ++r)
        C[cbase + (size_t)(grow0 + r) * HW + gcol] = acc[mr][nr][r] + bias[grow0 + r];
    }
  }
}

// ---------------- attention: per-thread (b, head, p), fp32 ----------------
// qkv layout: [b][t*256 + h*32 + d][p] fp32. Y (hi/lo bf16): [b][p][h*32+d].
template <int KSZ, int DIL, int H0>
__global__ __launch_bounds__(256) void attn_kernel(const float* __restrict__ qkv,
                                                   short* __restrict__ Yh,
                                                   short* __restrict__ Yl) {
  constexpr int R = KSZ / 2;
  const float SCALE = 0.17677669529663687f;       // 32^-0.5
  int tid = threadIdx.x;
  int p = blockIdx.x * 256 + tid;
  int hq = H0 + blockIdx.y;
  int b = blockIdx.z;
  const float* base = qkv + (size_t)b * 768 * HW;
  const float* Qp = base + (size_t)(hq * 32) * HW + p;
  const float* Kp = base + (size_t)(256 + hq * 32) * HW;
  const float* Vp = base + (size_t)(512 + hq * 32) * HW;

  float q[32];
  #pragma unroll
  for (int d = 0; d < 32; ++d) q[d] = Qp[(size_t)d * HW] * SCALE;

  float acc[32];
  #pragma unroll
  for (int d = 0; d < 32; ++d) acc[d] = 0.0f;
  float denom = 0.0f;

  int y = p >> 6, x = p & 63;

  for (int dy = -R; dy <= R; ++dy) {
    int ny = y + dy * DIL;
    for (int dx = -R; dx <= R; ++dx) {
      int nx = x + dx * DIL;
      if ((unsigned)ny < WDIM && (unsigned)nx < WDIM) {
        int pp = ny * WDIM + nx;
        float s0 = 0.f, s1 = 0.f, s2 = 0.f, s3 = 0.f;
        #pragma unroll
        for (int d = 0; d < 32; d += 4) {
          s0 += q[d + 0] * Kp[(size_t)(d + 0) * HW + pp];
          s1 += q[d + 1] * Kp[(size_t)(d + 1) * HW + pp];
          s2 += q[d + 2] * Kp[(size_t)(d + 2) * HW + pp];
          s3 += q[d + 3] * Kp[(size_t)(d + 3) * HW + pp];
        }
        float e = __expf((s0 + s1) + (s2 + s3));  // logits bounded; no max-sub needed
        denom += e;
        #pragma unroll
        for (int d = 0; d < 32; ++d) acc[d] += e * Vp[(size_t)d * HW + pp];
      } else {
        denom += 1.0f;                             // zero-padded unfold: logit=0 -> e=1, v=0
      }
    }
  }

  float inv = 1.0f / denom;
  size_t yo = ((size_t)b * HW + p) * 256 + hq * 32;
  #pragma unroll
  for (int d = 0; d < 32; ++d) {
    float v = acc[d] * inv;
    short hi = f2bf(v);
    Yh[yo + d] = hi;
    Yl[yo + d] = f2bf(v - bf2f(hi));
  }
}

// ---------------- launch ----------------
extern "C" void kernel_launch(void* const* d_in, const int* in_sizes, int n_in,
                              void* d_out, int out_size, void* d_ws, size_t ws_size,
                              hipStream_t stream) {
  const float* x  = (const float*)d_in[0];
  const float* w0 = (const float*)d_in[1];
  const float* b0 = (const float*)d_in[2];
  const float* w1 = (const float*)d_in[3];
  const float* b1 = (const float*)d_in[4];
  const float* w2 = (const float*)d_in[5];
  const float* b2 = (const float*)d_in[6];
  const float* pw = (const float*)d_in[7];
  const float* pb = (const float*)d_in[8];

  char* ws = (char*)d_ws;
  float* qkv = (float*)ws;  ws += (size_t)2 * 768 * HW * 4;   // 25.2 MB fp32
  short* XTh = (short*)ws;  ws += (size_t)2 * HW * 256 * 2;   // 4.2 MB
  short* XTl = (short*)ws;  ws += (size_t)2 * HW * 256 * 2;
  short* Yh  = (short*)ws;  ws += (size_t)2 * HW * 256 * 2;
  short* Yl  = (short*)ws;  ws += (size_t)2 * HW * 256 * 2;
  short* Wh  = (short*)ws;  ws += (size_t)768 * 256 * 2;
  short* Wl  = (short*)ws;  ws += (size_t)768 * 256 * 2;
  short* Ph  = (short*)ws;  ws += (size_t)256 * 256 * 2;
  short* Pl  = (short*)ws;  ws += (size_t)256 * 256 * 2;
  float* bsel= (float*)ws;  ws += 4096;

  prep_weights<<<1027, 256, 0, stream>>>(w0, w1, w2, b0, b1, b2, pw, Wh, Wl, Ph, Pl, bsel);
  transpose_x<<<dim3(128, 8, 2), dim3(32, 8), 0, stream>>>(x, XTh, XTl);
  gemm_split<<<dim3(32, 6, 2), 256, 0, stream>>>(Wh, Wl, XTh, XTl, bsel, qkv, 768);
  attn_kernel<5, 1, 0><<<dim3(16, 4, 2), 256, 0, stream>>>(qkv, Yh, Yl);
  attn_kernel<7, 2, 4><<<dim3(16, 3, 2), 256, 0, stream>>>(qkv, Yh, Yl);
  attn_kernel<9, 3, 7><<<dim3(16, 1, 2), 256, 0, stream>>>(qkv, Yh, Yl);
  gemm_split<<<dim3(32, 2, 2), 256, 0, stream>>>(Ph, Pl, Yh, Yl, pb, (float*)d_out, 256);
}

// Round 3
// 184.927 us; speedup vs baseline: 3.0433x; 3.0433x over previous
//
#include <hip/hip_runtime.h>
#include <hip/hip_bf16.h>
#include <stdint.h>
#include <stddef.h>

typedef short bf16x8 __attribute__((ext_vector_type(8)));
typedef float f32x4 __attribute__((ext_vector_type(4)));

#define HW 4096
#define WDIM 64

__device__ __forceinline__ short f2bf(float f) {
  union { __hip_bfloat16 b; short s; } u;
  u.b = __float2bfloat16(f);
  return u.s;
}
__device__ __forceinline__ float bf2f(short s) {
  union { unsigned u; float f; } u;
  u.u = ((unsigned)(unsigned short)s) << 16;
  return u.f;
}

// ---------------- prep: gather/convert weights (hi/lo split) + bias ----------------
__global__ void prep_weights(const float* __restrict__ w0, const float* __restrict__ w1,
                             const float* __restrict__ w2, const float* __restrict__ b0,
                             const float* __restrict__ b1, const float* __restrict__ b2,
                             const float* __restrict__ pw,
                             short* __restrict__ Wh, short* __restrict__ Wl,
                             short* __restrict__ Ph, short* __restrict__ Pl,
                             float* __restrict__ bias_sel) {
  int idx = blockIdx.x * 256 + threadIdx.x;
  if (idx < 768 * 256) {
    int j = idx >> 8;
    int h = (j & 255) >> 5;
    const float* w = (h < 4) ? w0 : ((h < 7) ? w1 : w2);
    float v = w[idx];
    short hi = f2bf(v);
    Wh[idx] = hi;
    Wl[idx] = f2bf(v - bf2f(hi));
  } else if (idx < 768 * 256 + 256 * 256) {
    int k = idx - 768 * 256;
    float v = pw[k];
    short hi = f2bf(v);
    Ph[k] = hi;
    Pl[k] = f2bf(v - bf2f(hi));
  } else if (idx < 768 * 256 + 256 * 256 + 768) {
    int j = idx - (768 * 256 + 256 * 256);
    int h = (j & 255) >> 5;
    const float* bb = (h < 4) ? b0 : ((h < 7) ? b1 : b2);
    bias_sel[j] = bb[j];
  }
}

// ---------------- transpose x: (B,256,HW) f32 -> XT (B,HW,256) bf16 hi/lo ----------------
__global__ void transpose_x(const float* __restrict__ x, short* __restrict__ XTh,
                            short* __restrict__ XTl) {
  __shared__ float tile[32][33];
  int b = blockIdx.z;
  int p0 = blockIdx.x * 32, c0 = blockIdx.y * 32;
  int tx = threadIdx.x, ty = threadIdx.y;       // 32 x 8
  const float* xb = x + (size_t)b * 256 * HW;
  #pragma unroll
  for (int i = 0; i < 32; i += 8)
    tile[ty + i][tx] = xb[(size_t)(c0 + ty + i) * HW + p0 + tx];
  __syncthreads();
  size_t ob = (size_t)b * HW * 256;
  #pragma unroll
  for (int i = 0; i < 32; i += 8) {
    float v = tile[tx][ty + i];
    short hi = f2bf(v);
    size_t o = ob + (size_t)(p0 + ty + i) * 256 + c0 + tx;
    XTh[o] = hi;
    XTl[o] = f2bf(v - bf2f(hi));
  }
}

// ---------------- split-bf16 MFMA GEMM (unchanged from round 2) ----------------
__global__ __launch_bounds__(256) void gemm_split(
    const short* __restrict__ Ah, const short* __restrict__ Al,
    const short* __restrict__ Bh, const short* __restrict__ Bl,
    const float* __restrict__ bias, float* __restrict__ C, int M) {
  constexpr int LD = 40;
  __shared__ short Ash[128 * LD], Asl[128 * LD], Bsh[128 * LD], Bsl[128 * LD];
  int tid = threadIdx.x;
  int b = blockIdx.z;
  size_t aoff = (size_t)blockIdx.y * 128 * 256;
  size_t boff = (size_t)b * HW * 256 + (size_t)blockIdx.x * 128 * 256;
  int lane = tid & 63, wid = tid >> 6;
  int wm = wid >> 1, wn = wid & 1;
  int il = lane & 15, kg = lane >> 4;
  f32x4 acc[4][4] = {};
  int row_s = tid >> 2;
  int kk_s = (tid & 3) * 8;

  for (int kt = 0; kt < 256; kt += 32) {
    size_t ga0 = aoff + (size_t)row_s * 256 + kt + kk_s;
    size_t ga1 = aoff + (size_t)(row_s + 64) * 256 + kt + kk_s;
    size_t gb0 = boff + (size_t)row_s * 256 + kt + kk_s;
    size_t gb1 = boff + (size_t)(row_s + 64) * 256 + kt + kk_s;
    bf16x8 rah0 = *(const bf16x8*)&Ah[ga0];
    bf16x8 rah1 = *(const bf16x8*)&Ah[ga1];
    bf16x8 ral0 = *(const bf16x8*)&Al[ga0];
    bf16x8 ral1 = *(const bf16x8*)&Al[ga1];
    bf16x8 rbh0 = *(const bf16x8*)&Bh[gb0];
    bf16x8 rbh1 = *(const bf16x8*)&Bh[gb1];
    bf16x8 rbl0 = *(const bf16x8*)&Bl[gb0];
    bf16x8 rbl1 = *(const bf16x8*)&Bl[gb1];
    __syncthreads();
    *(bf16x8*)&Ash[row_s * LD + kk_s] = rah0;
    *(bf16x8*)&Ash[(row_s + 64) * LD + kk_s] = rah1;
    *(bf16x8*)&Asl[row_s * LD + kk_s] = ral0;
    *(bf16x8*)&Asl[(row_s + 64) * LD + kk_s] = ral1;
    *(bf16x8*)&Bsh[row_s * LD + kk_s] = rbh0;
    *(bf16x8*)&Bsh[(row_s + 64) * LD + kk_s] = rbh1;
    *(bf16x8*)&Bsl[row_s * LD + kk_s] = rbl0;
    *(bf16x8*)&Bsl[(row_s + 64) * LD + kk_s] = rbl1;
    __syncthreads();
    bf16x8 afh[4], afl[4], bfh[4], bfl[4];
    #pragma unroll
    for (int mr = 0; mr < 4; ++mr) {
      int r = (wm * 64 + mr * 16 + il) * LD + kg * 8;
      afh[mr] = *(bf16x8*)&Ash[r];
      afl[mr] = *(bf16x8*)&Asl[r];
    }
    #pragma unroll
    for (int nr = 0; nr < 4; ++nr) {
      int r = (wn * 64 + nr * 16 + il) * LD + kg * 8;
      bfh[nr] = *(bf16x8*)&Bsh[r];
      bfl[nr] = *(bf16x8*)&Bsl[r];
    }
    #pragma unroll
    for (int mr = 0; mr < 4; ++mr)
      #pragma unroll
      for (int nr = 0; nr < 4; ++nr) {
        acc[mr][nr] = __builtin_amdgcn_mfma_f32_16x16x32_bf16(afh[mr], bfh[nr], acc[mr][nr], 0, 0, 0);
        acc[mr][nr] = __builtin_amdgcn_mfma_f32_16x16x32_bf16(afh[mr], bfl[nr], acc[mr][nr], 0, 0, 0);
        acc[mr][nr] = __builtin_amdgcn_mfma_f32_16x16x32_bf16(afl[mr], bfh[nr], acc[mr][nr], 0, 0, 0);
      }
  }

  size_t cbase = (size_t)b * M * HW;
  int m0 = blockIdx.y * 128, n0 = blockIdx.x * 128;
  #pragma unroll
  for (int mr = 0; mr < 4; ++mr) {
    #pragma unroll
    for (int nr = 0; nr < 4; ++nr) {
      int grow0 = m0 + wm * 64 + mr * 16 + kg * 4;
      int gcol = n0 + wn * 64 + nr * 16 + il;
      #pragma unroll
      for (int r = 0; r < 4; ++r)
        C[cbase + (size_t)(grow0 + r) * HW + gcol] = acc[mr][nr][r] + bias[grow0 + r];
    }
  }
}

// ---------------- merged attention: neighbor-split + LDS reduce ----------------
// qkv layout: [b][t*256+h*32+d][p] fp32. Block = 256 thr = G groups x PTILE positions.
// Thread (g,pl): partial (denom, acc[32]) over neighbors i = g, g+G, ... -> LDS -> reduce.
template <int KSZ, int DIL, int G, int PTILE>
__device__ __forceinline__ void attn_block(const float* __restrict__ base,
                                           short* __restrict__ Yh, short* __restrict__ Yl,
                                           float* __restrict__ sm, int hq, int p0,
                                           int tid, size_t ybase) {
  constexpr int R = KSZ / 2;
  constexpr int L = KSZ * KSZ;
  const float SCALE = 0.17677669529663687f;       // 32^-0.5
  int pl = tid & (PTILE - 1);
  int g = tid / PTILE;
  int p = p0 + pl;
  const float* Qp = base + (size_t)(hq * 32) * HW + p;
  const float* Kp = base + (size_t)(256 + hq * 32) * HW;
  const float* Vp = base + (size_t)(512 + hq * 32) * HW;

  float q[32];
  #pragma unroll
  for (int d = 0; d < 32; ++d) q[d] = Qp[(size_t)d * HW] * SCALE;

  float acc[32];
  #pragma unroll
  for (int d = 0; d < 32; ++d) acc[d] = 0.0f;
  float denom = 0.0f;

  int y = p >> 6, x = p & 63;

  for (int i = g; i < L; i += G) {
    int dy = i / KSZ - R;
    int dx = i % KSZ - R;
    int ny = y + dy * DIL, nx = x + dx * DIL;
    if ((unsigned)ny < WDIM && (unsigned)nx < WDIM) {
      int pp = ny * WDIM + nx;
      float s0 = 0.f, s1 = 0.f, s2 = 0.f, s3 = 0.f;
      #pragma unroll
      for (int d = 0; d < 32; d += 4) {
        s0 += q[d + 0] * Kp[(size_t)(d + 0) * HW + pp];
        s1 += q[d + 1] * Kp[(size_t)(d + 1) * HW + pp];
        s2 += q[d + 2] * Kp[(size_t)(d + 2) * HW + pp];
        s3 += q[d + 3] * Kp[(size_t)(d + 3) * HW + pp];
      }
      float e = __expf((s0 + s1) + (s2 + s3));
      denom += e;
      #pragma unroll
      for (int d = 0; d < 32; ++d) acc[d] += e * Vp[(size_t)d * HW + pp];
    } else {
      denom += 1.0f;                               // zero-padded unfold semantics
    }
  }

  // stash partials: 33 floats per thread, stride 33 words -> conflict-free
  float* mine = sm + tid * 33;
  mine[0] = denom;
  #pragma unroll
  for (int d = 0; d < 32; ++d) mine[1 + d] = acc[d];
  __syncthreads();

  // phase 2: thread (c, pl2) reduces G partials for d-chunk c
  constexpr int DPC = 32 / G;
  int pl2 = tid & (PTILE - 1);
  int c = tid / PTILE;
  float den = 0.f;
  #pragma unroll
  for (int gg = 0; gg < G; ++gg) den += sm[(gg * PTILE + pl2) * 33];
  float inv = 1.0f / den;
  size_t yb = ybase + (size_t)(p0 + pl2) * 256 + hq * 32 + c * DPC;
  #pragma unroll
  for (int j = 0; j < DPC; ++j) {
    float v = 0.f;
    #pragma unroll
    for (int gg = 0; gg < G; ++gg) v += sm[(gg * PTILE + pl2) * 33 + 1 + c * DPC + j];
    v *= inv;
    short hi = f2bf(v);
    Yh[yb + j] = hi;
    Yl[yb + j] = f2bf(v - bf2f(hi));
  }
}

// blocks: [0,256) ksz5 (G=2,PT=128), [256,640) ksz7 (G=4,PT=64), [640,896) ksz9 (G=8,PT=32)
__global__ __launch_bounds__(256) void attn_all(const float* __restrict__ qkv,
                                                short* __restrict__ Yh,
                                                short* __restrict__ Yl) {
  __shared__ float sm[256 * 33];
  int tid = threadIdx.x;
  int bx = blockIdx.x;
  if (bx < 256) {
    int tile = bx & 31;
    int rest = bx >> 5;
    int b = rest & 1, h = rest >> 1;                 // h in 0..3
    attn_block<5, 1, 2, 128>(qkv + (size_t)b * 768 * HW, Yh, Yl, sm, h, tile * 128, tid,
                             (size_t)b * HW * 256);
  } else if (bx < 640) {
    int s = bx - 256;
    int tile = s & 63;
    int rest = s >> 6;
    int b = rest & 1, h = 4 + (rest >> 1);           // h in 4..6
    attn_block<7, 2, 4, 64>(qkv + (size_t)b * 768 * HW, Yh, Yl, sm, h, tile * 64, tid,
                            (size_t)b * HW * 256);
  } else {
    int s = bx - 640;
    int tile = s & 127;
    int rest = s >> 7;
    int b = rest & 1;                                // h = 7
    attn_block<9, 3, 8, 32>(qkv + (size_t)b * 768 * HW, Yh, Yl, sm, 7, tile * 32, tid,
                            (size_t)b * HW * 256);
  }
}

// ---------------- launch ----------------
extern "C" void kernel_launch(void* const* d_in, const int* in_sizes, int n_in,
                              void* d_out, int out_size, void* d_ws, size_t ws_size,
                              hipStream_t stream) {
  const float* x  = (const float*)d_in[0];
  const float* w0 = (const float*)d_in[1];
  const float* b0 = (const float*)d_in[2];
  const float* w1 = (const float*)d_in[3];
  const float* b1 = (const float*)d_in[4];
  const float* w2 = (const float*)d_in[5];
  const float* b2 = (const float*)d_in[6];
  const float* pw = (const float*)d_in[7];
  const float* pb = (const float*)d_in[8];

  char* ws = (char*)d_ws;
  float* qkv = (float*)ws;  ws += (size_t)2 * 768 * HW * 4;
  short* XTh = (short*)ws;  ws += (size_t)2 * HW * 256 * 2;
  short* XTl = (short*)ws;  ws += (size_t)2 * HW * 256 * 2;
  short* Yh  = (short*)ws;  ws += (size_t)2 * HW * 256 * 2;
  short* Yl  = (short*)ws;  ws += (size_t)2 * HW * 256 * 2;
  short* Wh  = (short*)ws;  ws += (size_t)768 * 256 * 2;
  short* Wl  = (short*)ws;  ws += (size_t)768 * 256 * 2;
  short* Ph  = (short*)ws;  ws += (size_t)256 * 256 * 2;
  short* Pl  = (short*)ws;  ws += (size_t)256 * 256 * 2;
  float* bsel= (float*)ws;  ws += 4096;

  prep_weights<<<1027, 256, 0, stream>>>(w0, w1, w2, b0, b1, b2, pw, Wh, Wl, Ph, Pl, bsel);
  transpose_x<<<dim3(128, 8, 2), dim3(32, 8), 0, stream>>>(x, XTh, XTl);
  gemm_split<<<dim3(32, 6, 2), 256, 0, stream>>>(Wh, Wl, XTh, XTl, bsel, qkv, 768);
  attn_all<<<896, 256, 0, stream>>>(qkv, Yh, Yl);
  gemm_split<<<dim3(32, 2, 2), 256, 0, stream>>>(Ph, Pl, Yh, Yl, pb, (float*)d_out, 256);
}